// Round 4
// baseline (234.826 us; speedup 1.0000x reference)
//
#include <hip/hip_runtime.h>
#include <hip/hip_bf16.h>
#include <cmath>

// I/O: all inputs float32 (per reference setup_inputs), output float32.
// Internal compute: bf16 MFMA with fp32 accumulation.
//
// Workspace layout (64 MB total):
//  [0,16M)   WqkvT  [4096][2048] bf16   (rows: 0-2047 WqT, 2048-3071 WkT, 3072-4095 WvT)
//  [16,24M)  WoT    [2048][2048] bf16
//  [24,40M)  QKVraw [2048][4096] bf16
//  [40,48M)  Qn     [2048][2048] bf16   (post rms+rope, pre-scaled by QK_SCALE*log2e)
//  [48,52M)  Kn     [2048][1024] bf16
//  [52,56M)  Vt     [1024][2048] bf16   ([hkv*128 d][s])
//  [56,64M)  hsb    [2048][2048] bf16   (live: kernels 1-2)   }  overlaid,
//  [56,64M)  AT     [2048][2048] bf16   (live: kernels 4-5)   }  disjoint liveness
//
// R4: QKV GEMM moved to an 8-phase counted-vmcnt schedule (catalog T3+T4+T5),
// faithful to the m201 template: BM=256 x BN=128, 8 waves (4Mx2N, 64x64
// wave-tiles), BK=64, 96KB LDS double-buffer, 1 block/CU.  4 phases per
// K-tile, each {ds_read subtile | stage one 16KB chunk -> s_barrier ->
// setprio(1) 8xMFMA setprio(0) -> s_barrier}; vmcnt(2) ONLY at phase 0
// (after issuing next tile's chunk0) -- loads stay in flight across
// barriers.  R1 failed because it used counted vmcnt WITHOUT the phase
// interleave (the m196-documented coarse variant).

typedef __bf16 bf16x8 __attribute__((ext_vector_type(8)));
typedef float  f32x4  __attribute__((ext_vector_type(4)));

#define S_LEN    2048
#define NH       16
#define NKV      8
#define HDIM     128
#define WIN      1024
// QK_SCALE * log2(e): scores computed directly in log2 domain -> exp2
#define QK_SCALE_L2E 0.12751744595f
#define RMS_EPS  1e-6f

__device__ __forceinline__ void gld16(void* lds, const void* g) {
    __builtin_amdgcn_global_load_lds(
        (const __attribute__((address_space(1))) unsigned int*)g,
        (__attribute__((address_space(3))) unsigned int*)lds, 16, 0, 0);
}

__device__ __forceinline__ unsigned short f2bu(float x) {
    __hip_bfloat16 h = __float2bfloat16(x);
    return *(unsigned short*)&h;
}

// ---------------------------------------------------------------------------
// Fused: weight transpose + f32->bf16 (blocks 0..3071)  AND
//        hidden_states f32->bf16 convert (blocks 3072..5119).
// ---------------------------------------------------------------------------
__global__ __launch_bounds__(256) void trans_cvt_kernel(
    const float* __restrict__ Wq, const float* __restrict__ Wk,
    const float* __restrict__ Wv, const float* __restrict__ Wo,
    const float* __restrict__ hs,
    __hip_bfloat16* __restrict__ WqkvT, __hip_bfloat16* __restrict__ WoT,
    __hip_bfloat16* __restrict__ hsb)
{
    __shared__ __attribute__((aligned(16))) unsigned short tile[64][72]; // 144B rows
    int id = blockIdx.x;
    if (id >= 3072) {   // ---- hidden_states convert: 8 elems/thread ----
        size_t i = ((size_t)(id - 3072) * 256 + threadIdx.x) * 8;
        float4 a = *(const float4*)(hs + i);
        float4 b = *(const float4*)(hs + i + 4);
        unsigned short u[8] = { f2bu(a.x), f2bu(a.y), f2bu(a.z), f2bu(a.w),
                                f2bu(b.x), f2bu(b.y), f2bu(b.z), f2bu(b.w) };
        *(uint4*)(hsb + i) = *(uint4*)u;
        return;
    }
    const float* src; __hip_bfloat16* dst; int N, kt, nt;
    if (id < 1024)      { src = Wq; dst = WqkvT;                          N = 2048; kt = id >> 5;          nt = id & 31; }
    else if (id < 1536) { src = Wk; dst = WqkvT + (size_t)2048*2048;      N = 1024; kt = (id-1024) >> 4;   nt = (id-1024) & 15; }
    else if (id < 2048) { src = Wv; dst = WqkvT + (size_t)3072*2048;      N = 1024; kt = (id-1536) >> 4;   nt = (id-1536) & 15; }
    else                { src = Wo; dst = WoT;                            N = 2048; kt = (id-2048) >> 5;   nt = (id-2048) & 31; }
    int k0 = kt * 64, n0 = nt * 64;
    int tid = threadIdx.x;
#pragma unroll
    for (int p = 0; p < 2; ++p) {
        int c = p*256 + tid; int r = c >> 3, cc = (c & 7) * 8;
        const float* s = src + (size_t)(k0 + r)*N + n0 + cc;
        float4 a = *(const float4*)s;
        float4 b = *(const float4*)(s + 4);
        unsigned short u[8] = { f2bu(a.x), f2bu(a.y), f2bu(a.z), f2bu(a.w),
                                f2bu(b.x), f2bu(b.y), f2bu(b.z), f2bu(b.w) };
        *(uint4*)&tile[r][cc] = *(uint4*)u;
    }
    __syncthreads();
#pragma unroll
    for (int p = 0; p < 2; ++p) {
        int c = p*256 + tid; int r2 = c >> 3, c2 = (c & 7) * 8;
        uint4 o;
        o.x = tile[c2+0][r2] | ((unsigned)tile[c2+1][r2] << 16);
        o.y = tile[c2+2][r2] | ((unsigned)tile[c2+3][r2] << 16);
        o.z = tile[c2+4][r2] | ((unsigned)tile[c2+5][r2] << 16);
        o.w = tile[c2+6][r2] | ((unsigned)tile[c2+7][r2] << 16);
        *(uint4*)(dst + (size_t)(n0 + r2)*2048 + k0 + c2) = o;
    }
}

// ---------------------------------------------------------------------------
// QKV GEMM, 8-phase counted-vmcnt schedule.
// C[M][N] = A[M][K] * BT[N][K]^T, output bf16.
// BM=256 x BN=128, BK=64, 8 waves (4Mx2N, wave-tile 64x64), 96KB LDS,
// grid (N/128, M/256) = 256 blocks = 1/CU.
// K-tile staging = 3 chunks of 16KB (A-rows 0-127, A-rows 128-255, B),
// 2 gld16/thread each; chunks of tile t+1 issued in phases 0/1/2 of tile t.
// Phase 0 waits vmcnt(2) (retires exactly tile t's 6 loads; the 2 just
// issued stay in flight).  Buffer-reuse hazard covered by P3's post-barrier;
// data-validity by P0's vmcnt+barrier; sched_barrier(0) pins reads after it.
// ---------------------------------------------------------------------------
__global__ __launch_bounds__(512, 1) void gemm_qkv8_kernel(
    const __hip_bfloat16* __restrict__ A, const __hip_bfloat16* __restrict__ BT,
    __hip_bfloat16* __restrict__ C, int M, int N, int K)
{
    __shared__ __attribute__((aligned(16))) __hip_bfloat16 As[2][256*64];  // 2x32KB
    __shared__ __attribute__((aligned(16))) __hip_bfloat16 Bs[2][128*64];  // 2x16KB
    const int tid  = threadIdx.x;
    const int lane = tid & 63;
    const int wave = tid >> 6;                  // 0..7
    const int quad = lane >> 4, l15 = lane & 15;
    const int m0 = blockIdx.y * 256, n0 = blockIdx.x * 128;
    const int wm = (wave >> 1) * 64;            // 0,64,128,192
    const int wn = (wave & 1) * 64;             // 0,64
    const int sw = l15 & 7;                     // row-parity xor term (lane-const)

    f32x4 acc[4][4] = {};

    // stage one 16KB chunk of tile (k0) into buffer b.
    // c=0: A rows 0..127; c=1: A rows 128..255; c=2: B rows 0..127.
    auto stage_chunk = [&](int b, int k0, int c) {
        if (c < 2) {
#pragma unroll
            for (int q = 0; q < 2; ++q) {
                int L = q*512 + tid;
                int r = L >> 3, s = L & 7;
                int cs = s ^ (r & 7);
                gld16((char*)&As[b][0] + c*16384 + L*16,
                      A + (size_t)(m0 + c*128 + r)*K + k0 + cs*8);
            }
        } else {
#pragma unroll
            for (int q = 0; q < 2; ++q) {
                int L = q*512 + tid;
                int r = L >> 3, s = L & 7;
                int cs = s ^ (r & 7);
                gld16((char*)&Bs[b][0] + L*16,
                      BT + (size_t)(n0 + r)*K + k0 + cs*8);
            }
        }
    };

    const int NT = K >> 6;      // 32
    stage_chunk(0, 0, 0); stage_chunk(0, 0, 1); stage_chunk(0, 0, 2);

    int cur = 0;
    for (int kt = 0; kt < NT; ++kt, cur ^= 1) {
        const int nb = cur ^ 1;
        const bool hn = (kt + 1 < NT);
        const int nk = (kt + 1) << 6;
        const int slot0 = (quad ^ sw) * 8;          // ks=0
        const int slot1 = ((4 + quad) ^ sw) * 8;    // ks=1
        bf16x8 a0, a1, b0, b1, b2, b3;

        // ---------------- P0: ks=0, mt={0,1} ----------------
        if (hn) {
            stage_chunk(nb, nk, 0);
            asm volatile("s_waitcnt vmcnt(2)" ::: "memory");
        } else {
            asm volatile("s_waitcnt vmcnt(0)" ::: "memory");
        }
        __builtin_amdgcn_s_barrier();               // tile t fully staged
        __builtin_amdgcn_sched_barrier(0);
        b0 = *(const bf16x8*)(&Bs[cur][(wn +  0 + l15)*64 + slot0]);
        b1 = *(const bf16x8*)(&Bs[cur][(wn + 16 + l15)*64 + slot0]);
        b2 = *(const bf16x8*)(&Bs[cur][(wn + 32 + l15)*64 + slot0]);
        b3 = *(const bf16x8*)(&Bs[cur][(wn + 48 + l15)*64 + slot0]);
        a0 = *(const bf16x8*)(&As[cur][(wm +  0 + l15)*64 + slot0]);
        a1 = *(const bf16x8*)(&As[cur][(wm + 16 + l15)*64 + slot0]);
        __builtin_amdgcn_s_setprio(1);
        acc[0][0] = __builtin_amdgcn_mfma_f32_16x16x32_bf16(a0, b0, acc[0][0], 0, 0, 0);
        acc[0][1] = __builtin_amdgcn_mfma_f32_16x16x32_bf16(a0, b1, acc[0][1], 0, 0, 0);
        acc[0][2] = __builtin_amdgcn_mfma_f32_16x16x32_bf16(a0, b2, acc[0][2], 0, 0, 0);
        acc[0][3] = __builtin_amdgcn_mfma_f32_16x16x32_bf16(a0, b3, acc[0][3], 0, 0, 0);
        acc[1][0] = __builtin_amdgcn_mfma_f32_16x16x32_bf16(a1, b0, acc[1][0], 0, 0, 0);
        acc[1][1] = __builtin_amdgcn_mfma_f32_16x16x32_bf16(a1, b1, acc[1][1], 0, 0, 0);
        acc[1][2] = __builtin_amdgcn_mfma_f32_16x16x32_bf16(a1, b2, acc[1][2], 0, 0, 0);
        acc[1][3] = __builtin_amdgcn_mfma_f32_16x16x32_bf16(a1, b3, acc[1][3], 0, 0, 0);
        __builtin_amdgcn_s_setprio(0);
        __builtin_amdgcn_s_barrier();

        // ---------------- P1: ks=0, mt={2,3} ----------------
        a0 = *(const bf16x8*)(&As[cur][(wm + 32 + l15)*64 + slot0]);
        a1 = *(const bf16x8*)(&As[cur][(wm + 48 + l15)*64 + slot0]);
        if (hn) stage_chunk(nb, nk, 1);
        __builtin_amdgcn_s_barrier();
        __builtin_amdgcn_sched_barrier(0);
        __builtin_amdgcn_s_setprio(1);
        acc[2][0] = __builtin_amdgcn_mfma_f32_16x16x32_bf16(a0, b0, acc[2][0], 0, 0, 0);
        acc[2][1] = __builtin_amdgcn_mfma_f32_16x16x32_bf16(a0, b1, acc[2][1], 0, 0, 0);
        acc[2][2] = __builtin_amdgcn_mfma_f32_16x16x32_bf16(a0, b2, acc[2][2], 0, 0, 0);
        acc[2][3] = __builtin_amdgcn_mfma_f32_16x16x32_bf16(a0, b3, acc[2][3], 0, 0, 0);
        acc[3][0] = __builtin_amdgcn_mfma_f32_16x16x32_bf16(a1, b0, acc[3][0], 0, 0, 0);
        acc[3][1] = __builtin_amdgcn_mfma_f32_16x16x32_bf16(a1, b1, acc[3][1], 0, 0, 0);
        acc[3][2] = __builtin_amdgcn_mfma_f32_16x16x32_bf16(a1, b2, acc[3][2], 0, 0, 0);
        acc[3][3] = __builtin_amdgcn_mfma_f32_16x16x32_bf16(a1, b3, acc[3][3], 0, 0, 0);
        __builtin_amdgcn_s_setprio(0);
        __builtin_amdgcn_s_barrier();

        // ---------------- P2: ks=1, mt={0,1} ----------------
        b0 = *(const bf16x8*)(&Bs[cur][(wn +  0 + l15)*64 + slot1]);
        b1 = *(const bf16x8*)(&Bs[cur][(wn + 16 + l15)*64 + slot1]);
        b2 = *(const bf16x8*)(&Bs[cur][(wn + 32 + l15)*64 + slot1]);
        b3 = *(const bf16x8*)(&Bs[cur][(wn + 48 + l15)*64 + slot1]);
        a0 = *(const bf16x8*)(&As[cur][(wm +  0 + l15)*64 + slot1]);
        a1 = *(const bf16x8*)(&As[cur][(wm + 16 + l15)*64 + slot1]);
        if (hn) stage_chunk(nb, nk, 2);
        __builtin_amdgcn_s_barrier();
        __builtin_amdgcn_sched_barrier(0);
        __builtin_amdgcn_s_setprio(1);
        acc[0][0] = __builtin_amdgcn_mfma_f32_16x16x32_bf16(a0, b0, acc[0][0], 0, 0, 0);
        acc[0][1] = __builtin_amdgcn_mfma_f32_16x16x32_bf16(a0, b1, acc[0][1], 0, 0, 0);
        acc[0][2] = __builtin_amdgcn_mfma_f32_16x16x32_bf16(a0, b2, acc[0][2], 0, 0, 0);
        acc[0][3] = __builtin_amdgcn_mfma_f32_16x16x32_bf16(a0, b3, acc[0][3], 0, 0, 0);
        acc[1][0] = __builtin_amdgcn_mfma_f32_16x16x32_bf16(a1, b0, acc[1][0], 0, 0, 0);
        acc[1][1] = __builtin_amdgcn_mfma_f32_16x16x32_bf16(a1, b1, acc[1][1], 0, 0, 0);
        acc[1][2] = __builtin_amdgcn_mfma_f32_16x16x32_bf16(a1, b2, acc[1][2], 0, 0, 0);
        acc[1][3] = __builtin_amdgcn_mfma_f32_16x16x32_bf16(a1, b3, acc[1][3], 0, 0, 0);
        __builtin_amdgcn_s_setprio(0);
        __builtin_amdgcn_s_barrier();

        // ---------------- P3: ks=1, mt={2,3} ----------------
        a0 = *(const bf16x8*)(&As[cur][(wm + 32 + l15)*64 + slot1]);
        a1 = *(const bf16x8*)(&As[cur][(wm + 48 + l15)*64 + slot1]);
        __builtin_amdgcn_s_barrier();
        __builtin_amdgcn_sched_barrier(0);
        __builtin_amdgcn_s_setprio(1);
        acc[2][0] = __builtin_amdgcn_mfma_f32_16x16x32_bf16(a0, b0, acc[2][0], 0, 0, 0);
        acc[2][1] = __builtin_amdgcn_mfma_f32_16x16x32_bf16(a0, b1, acc[2][1], 0, 0, 0);
        acc[2][2] = __builtin_amdgcn_mfma_f32_16x16x32_bf16(a0, b2, acc[2][2], 0, 0, 0);
        acc[2][3] = __builtin_amdgcn_mfma_f32_16x16x32_bf16(a0, b3, acc[2][3], 0, 0, 0);
        acc[3][0] = __builtin_amdgcn_mfma_f32_16x16x32_bf16(a1, b0, acc[3][0], 0, 0, 0);
        acc[3][1] = __builtin_amdgcn_mfma_f32_16x16x32_bf16(a1, b1, acc[3][1], 0, 0, 0);
        acc[3][2] = __builtin_amdgcn_mfma_f32_16x16x32_bf16(a1, b2, acc[3][2], 0, 0, 0);
        acc[3][3] = __builtin_amdgcn_mfma_f32_16x16x32_bf16(a1, b3, acc[3][3], 0, 0, 0);
        __builtin_amdgcn_s_setprio(0);
        __builtin_amdgcn_s_barrier();               // protects buf reuse at next P0
    }

#pragma unroll
    for (int mt = 0; mt < 4; ++mt)
#pragma unroll
        for (int nt = 0; nt < 4; ++nt)
#pragma unroll
            for (int r = 0; r < 4; ++r) {
                int row = m0 + wm + mt*16 + quad*4 + r;
                int col = n0 + wn + nt*16 + l15;
                C[(size_t)row*N + col] = __float2bfloat16(acc[mt][nt][r]);
            }
}

// ---------------------------------------------------------------------------
// GEMM, 64x128 tile (output projection, M=N=2048): BM=64 x BN=128, BK=64,
// 48 KB LDS, 4 waves (2x2, wave-tile 32x64), grid 512 blocks = 2 blk/CU.
// ---------------------------------------------------------------------------
template <typename OT>
__global__ __launch_bounds__(256, 2) void gemm_bt64_kernel(
    const __hip_bfloat16* __restrict__ A, const __hip_bfloat16* __restrict__ BT,
    OT* __restrict__ C, int M, int N, int K)
{
    __shared__ __attribute__((aligned(16))) __hip_bfloat16 As[2][64*64];   // 2x8KB
    __shared__ __attribute__((aligned(16))) __hip_bfloat16 Bs[2][128*64];  // 2x16KB
    const int tid  = threadIdx.x;
    const int lane = tid & 63;
    const int wave = tid >> 6;
    const int quad = lane >> 4, l15 = lane & 15;
    const int m0 = blockIdx.y * 64, n0 = blockIdx.x * 128;
    const int wm = (wave >> 1) * 32, wn = (wave & 1) * 64;
    const int sw = l15 & 7;                     // row-parity xor term (lane-const)

    f32x4 acc[2][4] = {};

    auto stage = [&](int b, int k0) {
#pragma unroll
        for (int p = 0; p < 2; ++p) {           // A: 64 rows x 8 slots of 16B
            int L = p*256 + tid;
            int r = L >> 3, s = L & 7;
            int cs = s ^ (r & 7);
            gld16((char*)&As[b][0] + L*16, A + (size_t)(m0 + r)*K + k0 + cs*8);
        }
#pragma unroll
        for (int p = 0; p < 4; ++p) {           // B: 128 rows x 8 slots of 16B
            int L = p*256 + tid;
            int r = L >> 3, s = L & 7;
            int cs = s ^ (r & 7);
            gld16((char*)&Bs[b][0] + L*16, BT + (size_t)(n0 + r)*K + k0 + cs*8);
        }
    };

    const int NT = K >> 6;
    stage(0, 0);
    int cur = 0;
    for (int kt = 0; kt < NT; ++kt, cur ^= 1) {
        __syncthreads();                        // staging for cur done; waves synced
        if (kt + 1 < NT) stage(cur ^ 1, (kt + 1) << 6);
#pragma unroll
        for (int ks = 0; ks < 2; ++ks) {        // two 32-k steps within BK=64
            const int slot = ((ks*4 + quad) ^ sw) * 8;
            bf16x8 af[2], bfr[4];
#pragma unroll
            for (int t = 0; t < 2; ++t)
                af[t]  = *(const bf16x8*)(&As[cur][0] + (wm + t*16 + l15)*64 + slot);
#pragma unroll
            for (int t = 0; t < 4; ++t)
                bfr[t] = *(const bf16x8*)(&Bs[cur][0] + (wn + t*16 + l15)*64 + slot);
#pragma unroll
            for (int mt = 0; mt < 2; ++mt)
#pragma unroll
                for (int nt = 0; nt < 4; ++nt)
                    acc[mt][nt] = __builtin_amdgcn_mfma_f32_16x16x32_bf16(af[mt], bfr[nt], acc[mt][nt], 0, 0, 0);
        }
    }
#pragma unroll
    for (int mt = 0; mt < 2; ++mt)
#pragma unroll
        for (int nt = 0; nt < 4; ++nt)
#pragma unroll
            for (int r = 0; r < 4; ++r) {
                int row = m0 + wm + mt*16 + quad*4 + r;
                int col = n0 + wn + nt*16 + l15;
                if constexpr (__is_same(OT, float))
                    C[(size_t)row*N + col] = acc[mt][nt][r];
                else
                    C[(size_t)row*N + col] = __float2bfloat16(acc[mt][nt][r]);
            }
}

// ---------------------------------------------------------------------------
// Fused: RMSNorm+RoPE on Q,K rows of QKVraw (blocks 0..2047, one s each)
//        AND V transpose QKVraw -> Vt (blocks 2048..2559, 64x64 tiles).
// Q output pre-scaled by QK_SCALE*log2(e) (attention uses exp2 directly).
// ---------------------------------------------------------------------------
__global__ __launch_bounds__(256) void rms_vt_kernel(
    const __hip_bfloat16* __restrict__ qkv,
    const float* __restrict__ cosb, const float* __restrict__ sinb,
    const float* __restrict__ qsc,  const float* __restrict__ ksc,
    __hip_bfloat16* __restrict__ Qn, __hip_bfloat16* __restrict__ Kn,
    __hip_bfloat16* __restrict__ Vt)
{
    __shared__ __attribute__((aligned(16))) unsigned short tile[64][72];
    int id = blockIdx.x;
    if (id >= 2048) {   // ---- V transpose tile ----
        int t  = id - 2048;                 // 512 tiles: 32 (s) x 16 (v)
        int s0 = (t & 31) * 64;
        int v0 = (t >> 5) * 64;
        int tid = threadIdx.x;
#pragma unroll
        for (int p = 0; p < 2; ++p) {
            int c = p*256 + tid; int r = c >> 3, cc = (c & 7) * 8;
            uint4 v = *(const uint4*)(qkv + (size_t)(s0 + r)*4096 + 3072 + v0 + cc);
            *(uint4*)&tile[r][cc] = v;
        }
        __syncthreads();
#pragma unroll
        for (int p = 0; p < 2; ++p) {
            int c = p*256 + tid; int r2 = c >> 3, c2 = (c & 7) * 8;
            uint4 o;
            o.x = tile[c2+0][r2] | ((unsigned)tile[c2+1][r2] << 16);
            o.y = tile[c2+2][r2] | ((unsigned)tile[c2+3][r2] << 16);
            o.z = tile[c2+4][r2] | ((unsigned)tile[c2+5][r2] << 16);
            o.w = tile[c2+6][r2] | ((unsigned)tile[c2+7][r2] << 16);
            *(uint4*)(Vt + (size_t)(v0 + r2)*2048 + s0 + c2) = o;
        }
        return;
    }
    // ---- RMSNorm + RoPE ----
    int s = id;
    int wave = threadIdx.x >> 6, lane = threadIdx.x & 63;
    float c1 = cosb[s*128 + lane];
    float c2 = cosb[s*128 + 64 + lane];
    float s1 = sinb[s*128 + lane];
    float s2 = sinb[s*128 + 64 + lane];
    for (int u = wave; u < 24; u += 4) {
        bool isq = (u < 16);
        int h = isq ? u : u - 16;
        const __hip_bfloat16* x = qkv + (size_t)s*4096 + (isq ? h*128 : 2048 + h*128);
        float x1 = (float)x[lane], x2 = (float)x[lane + 64];
        float ss = x1*x1 + x2*x2;
#pragma unroll
        for (int off = 32; off; off >>= 1) ss += __shfl_xor(ss, off);
        float r = rsqrtf(ss * (1.0f/128.0f) + RMS_EPS);
        if (isq) r *= QK_SCALE_L2E;        // fold attn scale + log2e into Q
        const float* sc = isq ? qsc : ksc;
        float y1 = x1 * r * sc[lane];
        float y2 = x2 * r * sc[lane + 64];
        float o1 = y1*c1 - y2*s1;   // d < 64:  x*c - x[d+64]*s
        float o2 = y2*c2 + y1*s2;   // d >= 64: x*c + x[d-64]*s
        __hip_bfloat16* dst = isq ? (Qn + (size_t)s*2048 + h*128)
                                  : (Kn + (size_t)s*1024 + h*128);
        dst[lane]      = __float2bfloat16(o1);
        dst[lane + 64] = __float2bfloat16(o2);
    }
}

// ---------------------------------------------------------------------------
// Flash attention, sliding-window causal — m97-style LDS staging.
//  * Block = 4 waves x 16 q-rows = 64 q-rows of one head; grid 512 (2 blk/CU).
//  * K/V tiles staged into double-buffered LDS via global_load_lds width=16.
//  * XOR-swizzled LDS layouts; one barrier per tile; next staging issued
//    right after it (double buffer overlaps full tile compute).
//  * No online max (scores bounded by RMS-norm); p=exp2(s), per-lane row
//    sums, single cross-lane reduce in epilogue.
// ---------------------------------------------------------------------------
__global__ __launch_bounds__(256, 2) void attn_kernel(
    const __hip_bfloat16* __restrict__ Qn,  // [S][2048], pre-scaled (log2 domain)
    const __hip_bfloat16* __restrict__ Kn,  // [S][1024]
    const __hip_bfloat16* __restrict__ Vt,  // [1024][S]
    __hip_bfloat16* __restrict__ O)         // [S][2048]
{
    __shared__ __attribute__((aligned(16))) __hip_bfloat16 Ksm[2][64*128];  // 2x16KB
    __shared__ __attribute__((aligned(16))) __hip_bfloat16 Vsm[2][128*64];  // 2x16KB
    __shared__ __attribute__((aligned(16))) __hip_bfloat16 P[4][16][76];

    const int bx   = blockIdx.x;
    const int h    = bx & 15;
    const int qb   = 31 - (bx >> 4);          // long-window blocks dispatched first
    const int i0   = qb * 64;
    const int hk   = h >> 1;
    const int tid  = threadIdx.x, wave = tid >> 6, lane = tid & 63;
    const int quad = lane >> 4, l15 = lane & 15;
    const int ib   = i0 + wave * 16;

    const __hip_bfloat16* Kh = Kn + hk * HDIM;              // row stride 1024
    const __hip_bfloat16* Vh = Vt + (size_t)(hk * HDIM) * 2048;

    // Q fragments (A-operand), fixed for the block
    bf16x8 qf[4];
    const __hip_bfloat16* qbase = Qn + (size_t)(ib + l15)*2048 + h*HDIM + quad*8;
#pragma unroll
    for (int kk = 0; kk < 4; ++kk) qf[kk] = *(const bf16x8*)(qbase + kk*32);

    f32x4 o[8] = {};
    float lrow[4] = {0.f, 0.f, 0.f, 0.f};

    int j_lo = i0 - WIN; if (j_lo < 0) j_lo = 0;
    const int jstart = j_lo & ~63;
    const int jend   = i0;                    // diagonal tile start

    // ---- cooperative staging of one (K,V) tile pair into buffer b ----
    auto stage = [&](int b, int j0) {
#pragma unroll
        for (int p = 0; p < 4; ++p) {         // K: 64 rows x 16 chunks of 16B
            int L = p*256 + tid;
            int r = L >> 4;
            int c = (L & 15) ^ (r & 15);      // XOR swizzle
            gld16((char*)&Ksm[b][0] + L*16, Kh + (size_t)(j0 + r)*1024 + c*8);
        }
#pragma unroll
        for (int p = 0; p < 4; ++p) {         // V: 128 d-rows x 8 chunks of 16B
            int L = p*256 + tid;
            int dv = L >> 3;
            int c = (L & 7) ^ (dv & 7);       // XOR swizzle
            gld16((char*)&Vsm[b][0] + L*16, Vh + (size_t)dv*2048 + j0 + c*8);
        }
    };

    stage(0, jstart);
    int cur = 0;
    for (int j0 = jstart; j0 <= jend; j0 += 64, cur ^= 1) {
        __syncthreads();                      // drains staging vmcnt + syncs buffers
        if (j0 + 64 <= jend) stage(cur ^ 1, j0 + 64);

        // ---- S = Q K^T (16 x 64 per wave), frags from swizzled LDS ----
        f32x4 sacc[4] = {};
#pragma unroll
        for (int nt = 0; nt < 4; ++nt) {
            const int r = nt*16 + l15;
#pragma unroll
            for (int kk = 0; kk < 4; ++kk) {
                const int cc = (kk*4 + quad) ^ l15;   // swizzled chunk
                bf16x8 kfr = *(const bf16x8*)(&Ksm[cur][0] + r*128 + cc*8);
                sacc[nt] = __builtin_amdgcn_mfma_f32_16x16x32_bf16(qf[kk], kfr, sacc[nt], 0, 0, 0);
            }
        }

        // ---- p = exp2(s), P write, per-lane row-sum ----
        const bool need_mask = (j0 + 63 > ib) || (j0 < ib + 15 - WIN);
        if (need_mask) {
#pragma unroll
            for (int nt = 0; nt < 4; ++nt) {
                int j = j0 + nt*16 + l15;
#pragma unroll
                for (int r = 0; r < 4; ++r) {
                    int i = ib + quad*4 + r;
                    bool valid = (j <= i) && (i - j <= WIN);
                    float p = valid ? __builtin_exp2f(sacc[nt][r]) : 0.f;
                    lrow[r] += p;
                    P[wave][quad*4 + r][nt*16 + l15] = __float2bfloat16(p);
                }
            }
        } else {
#pragma unroll
            for (int nt = 0; nt < 4; ++nt)
#pragma unroll
                for (int r = 0; r < 4; ++r) {
                    float p = __builtin_exp2f(sacc[nt][r]);
                    lrow[r] += p;
                    P[wave][quad*4 + r][nt*16 + l15] = __float2bfloat16(p);
                }
        }

        // ---- O += P V (P per-wave, lgkm-ordered; V frags from swizzled LDS) ----
#pragma unroll
        for (int ks = 0; ks < 2; ++ks) {
            bf16x8 pf = *(const bf16x8*)&P[wave][l15][ks*32 + quad*8];
#pragma unroll
            for (int dt = 0; dt < 8; ++dt) {
                const int dv = dt*16 + l15;
                const int cc = (ks*4 + quad) ^ (l15 & 7);
                bf16x8 vfr = *(const bf16x8*)(&Vsm[cur][0] + dv*64 + cc*8);
                o[dt] = __builtin_amdgcn_mfma_f32_16x16x32_bf16(pf, vfr, o[dt], 0, 0, 0);
            }
        }
    }

    // ---- epilogue: single cross-lane reduce of lrow, normalize, store ----
#pragma unroll
    for (int r = 0; r < 4; ++r) {
        lrow[r] += __shfl_xor(lrow[r], 1);
        lrow[r] += __shfl_xor(lrow[r], 2);
        lrow[r] += __shfl_xor(lrow[r], 4);
        lrow[r] += __shfl_xor(lrow[r], 8);
        float inv = 1.0f / lrow[r];
        int row = ib + quad*4 + r;
#pragma unroll
        for (int dt = 0; dt < 8; ++dt)
            O[(size_t)row*2048 + h*HDIM + dt*16 + l15] = __float2bfloat16(o[dt][r] * inv);
    }
}

// ---------------------------------------------------------------------------
extern "C" void kernel_launch(void* const* d_in, const int* in_sizes, int n_in,
                              void* d_out, int out_size, void* d_ws, size_t ws_size,
                              hipStream_t stream)
{
    (void)in_sizes; (void)n_in; (void)out_size; (void)ws_size;
    const float* hs   = (const float*)d_in[0];
    const float* cosb = (const float*)d_in[1];
    const float* sinb = (const float*)d_in[2];
    const float* Wq   = (const float*)d_in[3];
    const float* Wk   = (const float*)d_in[4];
    const float* Wv   = (const float*)d_in[5];
    const float* Wo   = (const float*)d_in[6];
    const float* qs   = (const float*)d_in[7];
    const float* ks   = (const float*)d_in[8];

    char* ws = (char*)d_ws;
    __hip_bfloat16* WqkvT = (__hip_bfloat16*)(ws);
    __hip_bfloat16* WoT   = (__hip_bfloat16*)(ws + (16u << 20));
    __hip_bfloat16* QKV   = (__hip_bfloat16*)(ws + (24u << 20));
    __hip_bfloat16* Qn    = (__hip_bfloat16*)(ws + (40u << 20));
    __hip_bfloat16* Kn    = (__hip_bfloat16*)(ws + (48u << 20));
    __hip_bfloat16* Vt    = (__hip_bfloat16*)(ws + (52u << 20));
    __hip_bfloat16* hsb   = (__hip_bfloat16*)(ws + (56u << 20)); // overlaid with AT
    __hip_bfloat16* AT    = (__hip_bfloat16*)(ws + (56u << 20)); // disjoint liveness

    trans_cvt_kernel<<<dim3(5120), dim3(256), 0, stream>>>(Wq, Wk, Wv, Wo, hs, WqkvT, WoT, hsb);
    gemm_qkv8_kernel<<<dim3(32, 8), dim3(512), 0, stream>>>(hsb, WqkvT, QKV, 2048, 4096, 2048);
    rms_vt_kernel<<<dim3(2560), dim3(256), 0, stream>>>(QKV, cosb, sinb, qs, ks, Qn, Kn, Vt);
    attn_kernel<<<dim3(512), dim3(256), 0, stream>>>(Qn, Kn, Vt, AT);
    gemm_bt64_kernel<float><<<dim3(16, 32), dim3(256), 0, stream>>>(AT, WoT, (float*)d_out, 2048, 2048, 2048);
}

// Round 5
// 218.699 us; speedup vs baseline: 1.0737x; 1.0737x over previous
//
#include <hip/hip_runtime.h>
#include <hip/hip_bf16.h>
#include <cmath>

// I/O: all inputs float32 (per reference setup_inputs), output float32.
// Internal compute: bf16 MFMA with fp32 accumulation.
//
// Workspace layout (64 MB total):
//  [0,16M)   WqkvT  [4096][2048] bf16   (rows: 0-2047 WqT, 2048-3071 WkT, 3072-4095 WvT)
//  [16,24M)  WoT    [2048][2048] bf16
//  [24,40M)  QKVraw [2048][4096] bf16
//  [40,48M)  Qn     [2048][2048] bf16   (post rms+rope, pre-scaled by QK_SCALE*log2e)
//  [48,52M)  Kn     [2048][1024] bf16
//  [52,56M)  Vt     [1024][2048] bf16   ([hkv*128 d][s])
//  [56,64M)  hsb    [2048][2048] bf16   (live: kernels 1-2)   }  overlaid,
//  [56,64M)  AT     [2048][2048] bf16   (live: kernels 4-5)   }  disjoint liveness
//
// R5: GEMMs identical to R3 (221us baseline; gemm1 at its structural LDS
// ceiling).  New: (a) the 64x64 transpose tiles in trans_cvt/rms_vt were
// 16-way bank-conflicted on phase-2 reads (8-col granule stride 1152B === 0
// mod 128B) -- rewritten as u32-pair tiles [64][37] + granule-4 XOR swizzle,
// phase-2 = 8x ds_read_b32 (<=2-way, free) + bit-op pack of BOTH rows of a
// pair; (b) attn blockIdx remap so XCD x serves only kv-head x (K+V 0.75MB
// L2-resident per XCD, T1).

typedef __bf16 bf16x8 __attribute__((ext_vector_type(8)));
typedef float  f32x4  __attribute__((ext_vector_type(4)));

#define S_LEN    2048
#define NH       16
#define NKV      8
#define HDIM     128
#define WIN      1024
// QK_SCALE * log2(e): scores computed directly in log2 domain -> exp2
#define QK_SCALE_L2E 0.12751744595f
#define RMS_EPS  1e-6f

__device__ __forceinline__ void gld16(void* lds, const void* g) {
    __builtin_amdgcn_global_load_lds(
        (const __attribute__((address_space(1))) unsigned int*)g,
        (__attribute__((address_space(3))) unsigned int*)lds, 16, 0, 0);
}

__device__ __forceinline__ unsigned short f2bu(float x) {
    __hip_bfloat16 h = __float2bfloat16(x);
    return *(unsigned short*)&h;
}

// ---------------------------------------------------------------------------
// Fused: weight transpose + f32->bf16 (blocks 0..3071)  AND
//        hidden_states f32->bf16 convert (blocks 3072..5119).
// Transpose tile: u32 bf16-pairs, [64][37] words (row stride 148B spreads
// 8-row granules across banks), word-col granule-4 XOR swizzle by (row&7).
// Phase 1: 4x ds_write_b32 (~2-way max).  Phase 2: 8x ds_read_b32 (~2-way)
// + bit-pack -> two 16B rows per thread.  Old [64][72] u16 tile was 16-way
// conflicted on reads (5.7x, m136) over the 72MB weight path.
// ---------------------------------------------------------------------------
__global__ __launch_bounds__(256) void trans_cvt_kernel(
    const float* __restrict__ Wq, const float* __restrict__ Wk,
    const float* __restrict__ Wv, const float* __restrict__ Wo,
    const float* __restrict__ hs,
    __hip_bfloat16* __restrict__ WqkvT, __hip_bfloat16* __restrict__ WoT,
    __hip_bfloat16* __restrict__ hsb)
{
    __shared__ __attribute__((aligned(16))) unsigned tile32[64][37];
    int id = blockIdx.x;
    if (id >= 3072) {   // ---- hidden_states convert: 8 elems/thread ----
        size_t i = ((size_t)(id - 3072) * 256 + threadIdx.x) * 8;
        float4 a = *(const float4*)(hs + i);
        float4 b = *(const float4*)(hs + i + 4);
        unsigned short u[8] = { f2bu(a.x), f2bu(a.y), f2bu(a.z), f2bu(a.w),
                                f2bu(b.x), f2bu(b.y), f2bu(b.z), f2bu(b.w) };
        *(uint4*)(hsb + i) = *(uint4*)u;
        return;
    }
    const float* src; __hip_bfloat16* dst; int N, kt, nt;
    if (id < 1024)      { src = Wq; dst = WqkvT;                          N = 2048; kt = id >> 5;          nt = id & 31; }
    else if (id < 1536) { src = Wk; dst = WqkvT + (size_t)2048*2048;      N = 1024; kt = (id-1024) >> 4;   nt = (id-1024) & 15; }
    else if (id < 2048) { src = Wv; dst = WqkvT + (size_t)3072*2048;      N = 1024; kt = (id-1536) >> 4;   nt = (id-1536) & 15; }
    else                { src = Wo; dst = WoT;                            N = 2048; kt = (id-2048) >> 5;   nt = (id-2048) & 31; }
    int k0 = kt * 64, n0 = nt * 64;
    int tid = threadIdx.x;
#pragma unroll
    for (int p = 0; p < 2; ++p) {           // phase 1: read rows, cvt, swizzled store
        int c = p*256 + tid; int r = c >> 3, cc = (c & 7) * 8;
        const float* s = src + (size_t)(k0 + r)*N + n0 + cc;
        float4 a = *(const float4*)s;
        float4 b = *(const float4*)(s + 4);
        unsigned w0 = f2bu(a.x) | ((unsigned)f2bu(a.y) << 16);
        unsigned w1 = f2bu(a.z) | ((unsigned)f2bu(a.w) << 16);
        unsigned w2 = f2bu(b.x) | ((unsigned)f2bu(b.y) << 16);
        unsigned w3 = f2bu(b.z) | ((unsigned)f2bu(b.w) << 16);
        int Wb = (cc >> 1) ^ ((r & 7) << 2);        // granule-4 XOR
        tile32[r][Wb+0] = w0; tile32[r][Wb+1] = w1;
        tile32[r][Wb+2] = w2; tile32[r][Wb+3] = w3;
    }
    __syncthreads();
    {   // phase 2: each thread emits out-row pair (2*r2h, 2*r2h+1), 8 cols
        int r2h = tid >> 3;                 // 0..31  (input word-col)
        int c2  = (tid & 7) * 8;            // input-row chunk / out-col chunk
        unsigned lo[4], hi[4];
#pragma unroll
        for (int j = 0; j < 4; ++j) {
            int R0 = c2 + 2*j, R1 = R0 + 1;
            unsigned wa = tile32[R0][r2h ^ ((R0 & 7) << 2)];
            unsigned wb = tile32[R1][r2h ^ ((R1 & 7) << 2)];
            lo[j] = (wa & 0xFFFFu) | (wb << 16);
            hi[j] = (wa >> 16) | (wb & 0xFFFF0000u);
        }
        __hip_bfloat16* d0 = dst + (size_t)(n0 + 2*r2h)*2048 + k0 + c2;
        *(uint4*)d0          = *(uint4*)lo;
        *(uint4*)(d0 + 2048) = *(uint4*)hi;
    }
}

// ---------------------------------------------------------------------------
// GEMM: C[M][N] = A[M][K] * BT[N][K]^T.
// BM=128 x BN=128, BK=64, double-buffered LDS (64 KB), 4 waves (2x2,
// wave-tile 64x64), 2 blocks/CU.  The proven 42-48us/~800TF structure.
// ---------------------------------------------------------------------------
template <typename OT>
__global__ __launch_bounds__(256, 2) void gemm_bt_kernel(
    const __hip_bfloat16* __restrict__ A, const __hip_bfloat16* __restrict__ BT,
    OT* __restrict__ C, int M, int N, int K)
{
    __shared__ __attribute__((aligned(16))) __hip_bfloat16 As[2][128*64];  // 2x16KB
    __shared__ __attribute__((aligned(16))) __hip_bfloat16 Bs[2][128*64];  // 2x16KB
    const int tid  = threadIdx.x;
    const int lane = tid & 63;
    const int wave = tid >> 6;
    const int quad = lane >> 4, l15 = lane & 15;
    const int m0 = blockIdx.y * 128, n0 = blockIdx.x * 128;
    const int wm = (wave >> 1) * 64, wn = (wave & 1) * 64;
    const int sw = l15 & 7;                     // row-parity xor term (lane-const)

    f32x4 acc[4][4] = {};

    auto stage = [&](int b, int k0) {
#pragma unroll
        for (int p = 0; p < 4; ++p) {           // A: 128 rows x 8 slots of 16B
            int L = p*256 + tid;
            int r = L >> 3, s = L & 7;
            int cs = s ^ (r & 7);
            gld16((char*)&As[b][0] + L*16, A + (size_t)(m0 + r)*K + k0 + cs*8);
        }
#pragma unroll
        for (int p = 0; p < 4; ++p) {           // B: 128 rows x 8 slots of 16B
            int L = p*256 + tid;
            int r = L >> 3, s = L & 7;
            int cs = s ^ (r & 7);
            gld16((char*)&Bs[b][0] + L*16, BT + (size_t)(n0 + r)*K + k0 + cs*8);
        }
    };

    const int NT = K >> 6;
    stage(0, 0);
    int cur = 0;
    for (int kt = 0; kt < NT; ++kt, cur ^= 1) {
        __syncthreads();                        // staging for cur done; waves synced
        if (kt + 1 < NT) stage(cur ^ 1, (kt + 1) << 6);
#pragma unroll
        for (int ks = 0; ks < 2; ++ks) {        // two 32-k steps within BK=64
            const int slot = ((ks*4 + quad) ^ sw) * 8;
            bf16x8 af[4], bfr[4];
#pragma unroll
            for (int t = 0; t < 4; ++t) {
                af[t]  = *(const bf16x8*)(&As[cur][0] + (wm + t*16 + l15)*64 + slot);
                bfr[t] = *(const bf16x8*)(&Bs[cur][0] + (wn + t*16 + l15)*64 + slot);
            }
#pragma unroll
            for (int mt = 0; mt < 4; ++mt)
#pragma unroll
                for (int nt = 0; nt < 4; ++nt)
                    acc[mt][nt] = __builtin_amdgcn_mfma_f32_16x16x32_bf16(af[mt], bfr[nt], acc[mt][nt], 0, 0, 0);
        }
    }
#pragma unroll
    for (int mt = 0; mt < 4; ++mt)
#pragma unroll
        for (int nt = 0; nt < 4; ++nt)
#pragma unroll
            for (int r = 0; r < 4; ++r) {
                int row = m0 + wm + mt*16 + quad*4 + r;
                int col = n0 + wn + nt*16 + l15;
                if constexpr (__is_same(OT, float))
                    C[(size_t)row*N + col] = acc[mt][nt][r];
                else
                    C[(size_t)row*N + col] = __float2bfloat16(acc[mt][nt][r]);
            }
}

// ---------------------------------------------------------------------------
// GEMM, 64x128 tile (output projection, M=N=2048): BM=64 x BN=128, BK=64,
// 48 KB LDS, 4 waves (2x2, wave-tile 32x64), grid 512 blocks = 2 blk/CU.
// ---------------------------------------------------------------------------
template <typename OT>
__global__ __launch_bounds__(256, 2) void gemm_bt64_kernel(
    const __hip_bfloat16* __restrict__ A, const __hip_bfloat16* __restrict__ BT,
    OT* __restrict__ C, int M, int N, int K)
{
    __shared__ __attribute__((aligned(16))) __hip_bfloat16 As[2][64*64];   // 2x8KB
    __shared__ __attribute__((aligned(16))) __hip_bfloat16 Bs[2][128*64];  // 2x16KB
    const int tid  = threadIdx.x;
    const int lane = tid & 63;
    const int wave = tid >> 6;
    const int quad = lane >> 4, l15 = lane & 15;
    const int m0 = blockIdx.y * 64, n0 = blockIdx.x * 128;
    const int wm = (wave >> 1) * 32, wn = (wave & 1) * 64;
    const int sw = l15 & 7;                     // row-parity xor term (lane-const)

    f32x4 acc[2][4] = {};

    auto stage = [&](int b, int k0) {
#pragma unroll
        for (int p = 0; p < 2; ++p) {           // A: 64 rows x 8 slots of 16B
            int L = p*256 + tid;
            int r = L >> 3, s = L & 7;
            int cs = s ^ (r & 7);
            gld16((char*)&As[b][0] + L*16, A + (size_t)(m0 + r)*K + k0 + cs*8);
        }
#pragma unroll
        for (int p = 0; p < 4; ++p) {           // B: 128 rows x 8 slots of 16B
            int L = p*256 + tid;
            int r = L >> 3, s = L & 7;
            int cs = s ^ (r & 7);
            gld16((char*)&Bs[b][0] + L*16, BT + (size_t)(n0 + r)*K + k0 + cs*8);
        }
    };

    const int NT = K >> 6;
    stage(0, 0);
    int cur = 0;
    for (int kt = 0; kt < NT; ++kt, cur ^= 1) {
        __syncthreads();                        // staging for cur done; waves synced
        if (kt + 1 < NT) stage(cur ^ 1, (kt + 1) << 6);
#pragma unroll
        for (int ks = 0; ks < 2; ++ks) {        // two 32-k steps within BK=64
            const int slot = ((ks*4 + quad) ^ sw) * 8;
            bf16x8 af[2], bfr[4];
#pragma unroll
            for (int t = 0; t < 2; ++t)
                af[t]  = *(const bf16x8*)(&As[cur][0] + (wm + t*16 + l15)*64 + slot);
#pragma unroll
            for (int t = 0; t < 4; ++t)
                bfr[t] = *(const bf16x8*)(&Bs[cur][0] + (wn + t*16 + l15)*64 + slot);
#pragma unroll
            for (int mt = 0; mt < 2; ++mt)
#pragma unroll
                for (int nt = 0; nt < 4; ++nt)
                    acc[mt][nt] = __builtin_amdgcn_mfma_f32_16x16x32_bf16(af[mt], bfr[nt], acc[mt][nt], 0, 0, 0);
        }
    }
#pragma unroll
    for (int mt = 0; mt < 2; ++mt)
#pragma unroll
        for (int nt = 0; nt < 4; ++nt)
#pragma unroll
            for (int r = 0; r < 4; ++r) {
                int row = m0 + wm + mt*16 + quad*4 + r;
                int col = n0 + wn + nt*16 + l15;
                if constexpr (__is_same(OT, float))
                    C[(size_t)row*N + col] = acc[mt][nt][r];
                else
                    C[(size_t)row*N + col] = __float2bfloat16(acc[mt][nt][r]);
            }
}

// ---------------------------------------------------------------------------
// Fused: RMSNorm+RoPE on Q,K rows of QKVraw (blocks 0..2047, one s each)
//        AND V transpose QKVraw -> Vt (blocks 2048..2559, 64x64 tiles,
//        conflict-free u32-pair scheme as in trans_cvt).
// Q output pre-scaled by QK_SCALE*log2(e) (attention uses exp2 directly).
// ---------------------------------------------------------------------------
__global__ __launch_bounds__(256) void rms_vt_kernel(
    const __hip_bfloat16* __restrict__ qkv,
    const float* __restrict__ cosb, const float* __restrict__ sinb,
    const float* __restrict__ qsc,  const float* __restrict__ ksc,
    __hip_bfloat16* __restrict__ Qn, __hip_bfloat16* __restrict__ Kn,
    __hip_bfloat16* __restrict__ Vt)
{
    __shared__ __attribute__((aligned(16))) unsigned tile32[64][37];
    int id = blockIdx.x;
    if (id >= 2048) {   // ---- V transpose tile ----
        int t  = id - 2048;                 // 512 tiles: 32 (s) x 16 (v)
        int s0 = (t & 31) * 64;
        int v0 = (t >> 5) * 64;
        int tid = threadIdx.x;
#pragma unroll
        for (int p = 0; p < 2; ++p) {       // phase 1: swizzled u32 store
            int c = p*256 + tid; int r = c >> 3, cc = (c & 7) * 8;
            uint4 v = *(const uint4*)(qkv + (size_t)(s0 + r)*4096 + 3072 + v0 + cc);
            int Wb = (cc >> 1) ^ ((r & 7) << 2);
            tile32[r][Wb+0] = v.x; tile32[r][Wb+1] = v.y;
            tile32[r][Wb+2] = v.z; tile32[r][Wb+3] = v.w;
        }
        __syncthreads();
        {   // phase 2: out-row pair per thread
            int r2h = tid >> 3;
            int c2  = (tid & 7) * 8;
            unsigned lo[4], hi[4];
#pragma unroll
            for (int j = 0; j < 4; ++j) {
                int R0 = c2 + 2*j, R1 = R0 + 1;
                unsigned wa = tile32[R0][r2h ^ ((R0 & 7) << 2)];
                unsigned wb = tile32[R1][r2h ^ ((R1 & 7) << 2)];
                lo[j] = (wa & 0xFFFFu) | (wb << 16);
                hi[j] = (wa >> 16) | (wb & 0xFFFF0000u);
            }
            __hip_bfloat16* d0 = Vt + (size_t)(v0 + 2*r2h)*2048 + s0 + c2;
            *(uint4*)d0          = *(uint4*)lo;
            *(uint4*)(d0 + 2048) = *(uint4*)hi;
        }
        return;
    }
    // ---- RMSNorm + RoPE ----
    int s = id;
    int wave = threadIdx.x >> 6, lane = threadIdx.x & 63;
    float c1 = cosb[s*128 + lane];
    float c2 = cosb[s*128 + 64 + lane];
    float s1 = sinb[s*128 + lane];
    float s2 = sinb[s*128 + 64 + lane];
    for (int u = wave; u < 24; u += 4) {
        bool isq = (u < 16);
        int h = isq ? u : u - 16;
        const __hip_bfloat16* x = qkv + (size_t)s*4096 + (isq ? h*128 : 2048 + h*128);
        float x1 = (float)x[lane], x2 = (float)x[lane + 64];
        float ss = x1*x1 + x2*x2;
#pragma unroll
        for (int off = 32; off; off >>= 1) ss += __shfl_xor(ss, off);
        float r = rsqrtf(ss * (1.0f/128.0f) + RMS_EPS);
        if (isq) r *= QK_SCALE_L2E;        // fold attn scale + log2e into Q
        const float* sc = isq ? qsc : ksc;
        float y1 = x1 * r * sc[lane];
        float y2 = x2 * r * sc[lane + 64];
        float o1 = y1*c1 - y2*s1;   // d < 64:  x*c - x[d+64]*s
        float o2 = y2*c2 + y1*s2;   // d >= 64: x*c + x[d-64]*s
        __hip_bfloat16* dst = isq ? (Qn + (size_t)s*2048 + h*128)
                                  : (Kn + (size_t)s*1024 + h*128);
        dst[lane]      = __float2bfloat16(o1);
        dst[lane + 64] = __float2bfloat16(o2);
    }
}

// ---------------------------------------------------------------------------
// Flash attention, sliding-window causal — m97-style LDS staging.
//  * Block = 4 waves x 16 q-rows = 64 q-rows of one head; grid 512 (2 blk/CU).
//  * XCD-aware head mapping: XCD x (= bx%8) serves only heads {2x, 2x+1},
//    i.e. kv-head x -> its K+V (0.75 MB) stays L2-resident per XCD (T1).
//  * K/V tiles staged into double-buffered LDS via global_load_lds width=16.
//  * XOR-swizzled LDS layouts; one barrier per tile; next staging issued
//    right after it (double buffer overlaps full tile compute).
//  * No online max (scores bounded by RMS-norm); p=exp2(s), per-lane row
//    sums, single cross-lane reduce in epilogue.
// ---------------------------------------------------------------------------
__global__ __launch_bounds__(256, 2) void attn_kernel(
    const __hip_bfloat16* __restrict__ Qn,  // [S][2048], pre-scaled (log2 domain)
    const __hip_bfloat16* __restrict__ Kn,  // [S][1024]
    const __hip_bfloat16* __restrict__ Vt,  // [1024][S]
    __hip_bfloat16* __restrict__ O)         // [S][2048]
{
    __shared__ __attribute__((aligned(16))) __hip_bfloat16 Ksm[2][64*128];  // 2x16KB
    __shared__ __attribute__((aligned(16))) __hip_bfloat16 Vsm[2][128*64];  // 2x16KB
    __shared__ __attribute__((aligned(16))) __hip_bfloat16 P[4][16][76];

    const int bx   = blockIdx.x;
    const int h    = ((bx & 7) << 1) | ((bx >> 3) & 1);   // XCD bx%8 -> kv-head bx%8
    const int qb   = 31 - (bx >> 4);          // long-window blocks dispatched first
    const int i0   = qb * 64;
    const int hk   = h >> 1;
    const int tid  = threadIdx.x, wave = tid >> 6, lane = tid & 63;
    const int quad = lane >> 4, l15 = lane & 15;
    const int ib   = i0 + wave * 16;

    const __hip_bfloat16* Kh = Kn + hk * HDIM;              // row stride 1024
    const __hip_bfloat16* Vh = Vt + (size_t)(hk * HDIM) * 2048;

    // Q fragments (A-operand), fixed for the block
    bf16x8 qf[4];
    const __hip_bfloat16* qbase = Qn + (size_t)(ib + l15)*2048 + h*HDIM + quad*8;
#pragma unroll
    for (int kk = 0; kk < 4; ++kk) qf[kk] = *(const bf16x8*)(qbase + kk*32);

    f32x4 o[8] = {};
    float lrow[4] = {0.f, 0.f, 0.f, 0.f};

    int j_lo = i0 - WIN; if (j_lo < 0) j_lo = 0;
    const int jstart = j_lo & ~63;
    const int jend   = i0;                    // diagonal tile start

    // ---- cooperative staging of one (K,V) tile pair into buffer b ----
    auto stage = [&](int b, int j0) {
#pragma unroll
        for (int p = 0; p < 4; ++p) {         // K: 64 rows x 16 chunks of 16B
            int L = p*256 + tid;
            int r = L >> 4;
            int c = (L & 15) ^ (r & 15);      // XOR swizzle
            gld16((char*)&Ksm[b][0] + L*16, Kh + (size_t)(j0 + r)*1024 + c*8);
        }
#pragma unroll
        for (int p = 0; p < 4; ++p) {         // V: 128 d-rows x 8 chunks of 16B
            int L = p*256 + tid;
            int dv = L >> 3;
            int c = (L & 7) ^ (dv & 7);       // XOR swizzle
            gld16((char*)&Vsm[b][0] + L*16, Vh + (size_t)dv*2048 + j0 + c*8);
        }
    };

    stage(0, jstart);
    int cur = 0;
    for (int j0 = jstart; j0 <= jend; j0 += 64, cur ^= 1) {
        __syncthreads();                      // drains staging vmcnt + syncs buffers
        if (j0 + 64 <= jend) stage(cur ^ 1, j0 + 64);

        // ---- S = Q K^T (16 x 64 per wave), frags from swizzled LDS ----
        f32x4 sacc[4] = {};
#pragma unroll
        for (int nt = 0; nt < 4; ++nt) {
            const int r = nt*16 + l15;
#pragma unroll
            for (int kk = 0; kk < 4; ++kk) {
                const int cc = (kk*4 + quad) ^ l15;   // swizzled chunk
                bf16x8 kfr = *(const bf16x8*)(&Ksm[cur][0] + r*128 + cc*8);
                sacc[nt] = __builtin_amdgcn_mfma_f32_16x16x32_bf16(qf[kk], kfr, sacc[nt], 0, 0, 0);
            }
        }

        // ---- p = exp2(s), P write, per-lane row-sum ----
        const bool need_mask = (j0 + 63 > ib) || (j0 < ib + 15 - WIN);
        if (need_mask) {
#pragma unroll
            for (int nt = 0; nt < 4; ++nt) {
                int j = j0 + nt*16 + l15;
#pragma unroll
                for (int r = 0; r < 4; ++r) {
                    int i = ib + quad*4 + r;
                    bool valid = (j <= i) && (i - j <= WIN);
                    float p = valid ? __builtin_exp2f(sacc[nt][r]) : 0.f;
                    lrow[r] += p;
                    P[wave][quad*4 + r][nt*16 + l15] = __float2bfloat16(p);
                }
            }
        } else {
#pragma unroll
            for (int nt = 0; nt < 4; ++nt)
#pragma unroll
                for (int r = 0; r < 4; ++r) {
                    float p = __builtin_exp2f(sacc[nt][r]);
                    lrow[r] += p;
                    P[wave][quad*4 + r][nt*16 + l15] = __float2bfloat16(p);
                }
        }

        // ---- O += P V (P per-wave, lgkm-ordered; V frags from swizzled LDS) ----
#pragma unroll
        for (int ks = 0; ks < 2; ++ks) {
            bf16x8 pf = *(const bf16x8*)&P[wave][l15][ks*32 + quad*8];
#pragma unroll
            for (int dt = 0; dt < 8; ++dt) {
                const int dv = dt*16 + l15;
                const int cc = (ks*4 + quad) ^ (l15 & 7);
                bf16x8 vfr = *(const bf16x8*)(&Vsm[cur][0] + dv*64 + cc*8);
                o[dt] = __builtin_amdgcn_mfma_f32_16x16x32_bf16(pf, vfr, o[dt], 0, 0, 0);
            }
        }
    }

    // ---- epilogue: single cross-lane reduce of lrow, normalize, store ----
#pragma unroll
    for (int r = 0; r < 4; ++r) {
        lrow[r] += __shfl_xor(lrow[r], 1);
        lrow[r] += __shfl_xor(lrow[r], 2);
        lrow[r] += __shfl_xor(lrow[r], 4);
        lrow[r] += __shfl_xor(lrow[r], 8);
        float inv = 1.0f / lrow[r];
        int row = ib + quad*4 + r;
#pragma unroll
        for (int dt = 0; dt < 8; ++dt)
            O[(size_t)row*2048 + h*HDIM + dt*16 + l15] = __float2bfloat16(o[dt][r] * inv);
    }
}

// ---------------------------------------------------------------------------
extern "C" void kernel_launch(void* const* d_in, const int* in_sizes, int n_in,
                              void* d_out, int out_size, void* d_ws, size_t ws_size,
                              hipStream_t stream)
{
    (void)in_sizes; (void)n_in; (void)out_size; (void)ws_size;
    const float* hs   = (const float*)d_in[0];
    const float* cosb = (const float*)d_in[1];
    const float* sinb = (const float*)d_in[2];
    const float* Wq   = (const float*)d_in[3];
    const float* Wk   = (const float*)d_in[4];
    const float* Wv   = (const float*)d_in[5];
    const float* Wo   = (const float*)d_in[6];
    const float* qs   = (const float*)d_in[7];
    const float* ks   = (const float*)d_in[8];

    char* ws = (char*)d_ws;
    __hip_bfloat16* WqkvT = (__hip_bfloat16*)(ws);
    __hip_bfloat16* WoT   = (__hip_bfloat16*)(ws + (16u << 20));
    __hip_bfloat16* QKV   = (__hip_bfloat16*)(ws + (24u << 20));
    __hip_bfloat16* Qn    = (__hip_bfloat16*)(ws + (40u << 20));
    __hip_bfloat16* Kn    = (__hip_bfloat16*)(ws + (48u << 20));
    __hip_bfloat16* Vt    = (__hip_bfloat16*)(ws + (52u << 20));
    __hip_bfloat16* hsb   = (__hip_bfloat16*)(ws + (56u << 20)); // overlaid with AT
    __hip_bfloat16* AT    = (__hip_bfloat16*)(ws + (56u << 20)); // disjoint liveness

    trans_cvt_kernel<<<dim3(5120), dim3(256), 0, stream>>>(Wq, Wk, Wv, Wo, hs, WqkvT, WoT, hsb);
    gemm_bt_kernel<__hip_bfloat16><<<dim3(32, 16), dim3(256), 0, stream>>>(hsb, WqkvT, QKV, 2048, 4096, 2048);
    rms_vt_kernel<<<dim3(2560), dim3(256), 0, stream>>>(QKV, cosb, sinb, qs, ks, Qn, Kn, Vt);
    attn_kernel<<<dim3(512), dim3(256), 0, stream>>>(Qn, Kn, Vt, AT);
    gemm_bt64_kernel<float><<<dim3(16, 32), dim3(256), 0, stream>>>(AT, WoT, (float*)d_out, 2048, 2048, 2048);
}